// Round 11
// baseline (480.785 us; speedup 1.0000x reference)
//
#include <hip/hip_runtime.h>
#include <hip/hip_bf16.h>

#define D_ 64
#define HW_ 4096
#define K_ 1024
#define NPTS_ 65536
#define QOUT_ 4194304      // B*D*H*W, offset of idx region in d_out
#define DELTA 0.006f       // ambiguity margin; worst-case bf16-split diff ~2e-3
#define INF_ 3.4e38f
#define KSPL 4             // K splits -> 256 codes per block, 64 KB LDS tile
#define KPB  256           // codes per block

typedef short bf16x8 __attribute__((ext_vector_type(8)));
typedef float f32x4 __attribute__((ext_vector_type(4)));

__device__ __forceinline__ void gload_lds16(const float* g, float* l) {
    __builtin_amdgcn_global_load_lds((const __attribute__((address_space(1))) void*)g,
                                     (__attribute__((address_space(3))) void*)l, 16, 0, 0);
}
__device__ __forceinline__ void gload_lds4(const float* g, float* l) {
    __builtin_amdgcn_global_load_lds((const __attribute__((address_space(1))) void*)g,
                                     (__attribute__((address_space(3))) void*)l, 4, 0, 0);
}

// ---- pack kernel: cnorm + bf16 hi/lo split of (-2*cb) in MFMA-fragment order ----
// P layout (shorts): [gch(64)][ks(2)][lvl(2)][lane(64)][8]
//   code j = gch*16 + (l&15), dims d = ks*32 + (l>>4)*8 + i
__global__ __launch_bounds__(256) void vq_pack(const float* __restrict__ cb,
                                               float* __restrict__ cnorm,
                                               short* __restrict__ P) {
    const int t = blockIdx.x * 256 + threadIdx.x;   // 0..4095
    const int gch = t >> 6, l = t & 63;
    const int j  = gch * 16 + (l & 15);
    const int dg = l >> 4;
#pragma unroll
    for (int s = 0; s < 2; ++s) {
        const float* src = cb + j * D_ + s * 32 + dg * 8;
        short hb[8], lb[8];
#pragma unroll
        for (int i = 0; i < 8; ++i) {
            const float v = -2.f * src[i];
            __hip_bfloat16 h = __float2bfloat16(v);
            hb[i] = *(const short*)&h;
            const float r = v - __bfloat162float(h);
            __hip_bfloat16 lo = __float2bfloat16(r);
            lb[i] = *(const short*)&lo;
        }
        short* dh = P + ((size_t)((gch * 2 + s) * 2 + 0) * 64 + l) * 8;
        short* dl = P + ((size_t)((gch * 2 + s) * 2 + 1) * 64 + l) * 8;
#pragma unroll
        for (int i = 0; i < 8; ++i) { dh[i] = hb[i]; dl[i] = lb[i]; }
    }
    if (t < K_) {
        const float4* r = (const float4*)(cb + (size_t)t * D_);
        float s0 = 0.f, s1 = 0.f, s2 = 0.f, s3 = 0.f;
#pragma unroll
        for (int i = 0; i < 16; ++i) {
            float4 v = r[i];
            s0 = fmaf(v.x, v.x, s0); s1 = fmaf(v.y, v.y, s1);
            s2 = fmaf(v.z, v.z, s2); s3 = fmaf(v.w, v.w, s3);
        }
        cnorm[t] = (s0 + s1) + (s2 + s3);
    }
}

// ---- main: K-split MFMA GEMM-argmin, 64 KB codebook tile resident in LDS ----
// KSPL=4 + XCD swizzle. Full ch-unroll (R5-proven with scalar split; R9's
// spill was the cvt_pk+unroll combo) + chain-split accumulators: four
// independent 3-deep MFMA chains instead of two 6-deep ones.
// Spill tripwire: WRITE_SIZE must stay ~3.3 MB.
__global__ __launch_bounds__(512, 4) void vq_main(const float* __restrict__ x,
                                                  const float* __restrict__ cnorm_g,
                                                  const short* __restrict__ P,
                                                  float* __restrict__ out) {
    __shared__ short cbuf[16 * 2 * 2 * 64 * 8];   // 64 KB
    __shared__ float cnt[KPB];                    // 1 KB

    const int tid  = threadIdx.x;
    const int lane = tid & 63;
    const int wid  = tid >> 6;
    const int orig = blockIdx.x;                  // 0..1023
    const int xcd  = orig & 7;
    const int j    = orig >> 3;                   // 0..127
    const int pg   = xcd * 32 + (j & 31);         // point-group, L2-local per XCD
    const int sp   = j >> 5;                      // split 0..3
    const int bb   = pg >> 4;
    const int hw0  = (pg & 15) << 8;

    // stage packed codebook tile (64 KB) + cnorm slice, once
    {
        const float* Pf = (const float*)P + (size_t)sp * 16384;
        float* cf = (float*)cbuf;
#pragma unroll
        for (int r = 0; r < 8; ++r)
            gload_lds16(Pf + r * 2048 + wid * 256 + lane * 4, cf + r * 2048 + wid * 256);
        if (wid < 4) gload_lds4(cnorm_g + sp * KPB + wid * 64 + lane, cnt + wid * 64);
    }

    // load + split x fragments (persistent): lane holds point (l&15), dims (l>>4)*8..+7
    bf16x8 ah[2][2], al[2][2];
    {
        const float* xb = x + (size_t)bb * (D_ * HW_) + hw0;
#pragma unroll
        for (int t = 0; t < 2; ++t) {
            const int p_l = wid * 32 + t * 16 + (lane & 15);
#pragma unroll
            for (int s = 0; s < 2; ++s) {
                const int d0 = s * 32 + (lane >> 4) * 8;
#pragma unroll
                for (int i = 0; i < 8; ++i) {
                    const float v = xb[(size_t)(d0 + i) * HW_ + p_l];
                    __hip_bfloat16 h = __float2bfloat16(v);
                    ah[t][s][i] = *(const short*)&h;
                    const float r = v - __bfloat162float(h);
                    __hip_bfloat16 lo = __float2bfloat16(r);
                    al[t][s][i] = *(const short*)&lo;
                }
            }
        }
    }
    asm volatile("s_waitcnt vmcnt(0)" ::: "memory");
    __syncthreads();

    float m1[8], m2[8];
    int   i1[8];
#pragma unroll
    for (int q = 0; q < 8; ++q) { m1[q] = INF_; m2[q] = INF_; i1[q] = 0; }

    const bf16x8* fr = (const bf16x8*)cbuf;
#pragma unroll
    for (int ch = 0; ch < 16; ++ch) {
        const float cn = cnt[ch * 16 + (lane & 15)];
        bf16x8 bh0 = fr[((ch * 2 + 0) * 2 + 0) * 64 + lane];
        bf16x8 bl0 = fr[((ch * 2 + 0) * 2 + 1) * 64 + lane];
        bf16x8 bh1 = fr[((ch * 2 + 1) * 2 + 0) * 64 + lane];
        bf16x8 bl1 = fr[((ch * 2 + 1) * 2 + 1) * 64 + lane];
        f32x4 a0a = {0.f, 0.f, 0.f, 0.f};   // t=0, s=0 terms (3-chain)
        f32x4 a0b = {0.f, 0.f, 0.f, 0.f};   // t=0, s=1 terms (3-chain)
        f32x4 a1a = {0.f, 0.f, 0.f, 0.f};   // t=1, s=0 terms
        f32x4 a1b = {0.f, 0.f, 0.f, 0.f};   // t=1, s=1 terms
        // round-robin across 4 independent chains
        a0a = __builtin_amdgcn_mfma_f32_16x16x32_bf16(ah[0][0], bh0, a0a, 0, 0, 0);
        a1a = __builtin_amdgcn_mfma_f32_16x16x32_bf16(ah[1][0], bh0, a1a, 0, 0, 0);
        a0b = __builtin_amdgcn_mfma_f32_16x16x32_bf16(ah[0][1], bh1, a0b, 0, 0, 0);
        a1b = __builtin_amdgcn_mfma_f32_16x16x32_bf16(ah[1][1], bh1, a1b, 0, 0, 0);
        a0a = __builtin_amdgcn_mfma_f32_16x16x32_bf16(al[0][0], bh0, a0a, 0, 0, 0);
        a1a = __builtin_amdgcn_mfma_f32_16x16x32_bf16(al[1][0], bh0, a1a, 0, 0, 0);
        a0b = __builtin_amdgcn_mfma_f32_16x16x32_bf16(al[0][1], bh1, a0b, 0, 0, 0);
        a1b = __builtin_amdgcn_mfma_f32_16x16x32_bf16(al[1][1], bh1, a1b, 0, 0, 0);
        a0a = __builtin_amdgcn_mfma_f32_16x16x32_bf16(ah[0][0], bl0, a0a, 0, 0, 0);
        a1a = __builtin_amdgcn_mfma_f32_16x16x32_bf16(ah[1][0], bl0, a1a, 0, 0, 0);
        a0b = __builtin_amdgcn_mfma_f32_16x16x32_bf16(ah[0][1], bl1, a0b, 0, 0, 0);
        a1b = __builtin_amdgcn_mfma_f32_16x16x32_bf16(ah[1][1], bl1, a1b, 0, 0, 0);

        const int kc = sp * KPB + ch * 16 + (lane & 15);
#pragma unroll
        for (int t = 0; t < 2; ++t)
#pragma unroll
            for (int r = 0; r < 4; ++r) {
                const int q = t * 4 + r;
                const float d2 = cn + ((t == 0) ? (a0a[r] + a0b[r]) : (a1a[r] + a1b[r]));
                const bool lt = d2 < m1[q];
                m2[q] = fminf(m2[q], fmaxf(m1[q], d2));  // min(m2, loser of (m1,d2))
                m1[q] = fminf(m1[q], d2);
                i1[q] = lt ? kc : i1[q];
            }
    }

    // cross-lane (m1,i1,m2) reduce over the 16 lanes sharing (lane>>4)
#pragma unroll
    for (int q = 0; q < 8; ++q) {
        float a1 = m1[q], a2 = m2[q];
        int   ai = i1[q];
#pragma unroll
        for (int m = 1; m < 16; m <<= 1) {
            const float o1 = __shfl_xor(a1, m);
            const int   oi = __shfl_xor(ai, m);
            const float o2 = __shfl_xor(a2, m);
            const float nm2 = fminf(fminf(a2, o2), fmaxf(a1, o1));
            if (o1 < a1 || (o1 == a1 && oi < ai)) { a1 = o1; ai = oi; }
            a2 = nm2;
        }
        if ((lane & 15) == 0) {
            const int t = q >> 2, r = q & 3;
            const int pt = wid * 32 + t * 16 + 4 * (lane >> 4) + r;
            float* cb_col = out + (size_t)bb * (D_ * HW_) + hw0 + pt;
            cb_col[(size_t)(3 * sp + 0) * HW_] = a1;
            cb_col[(size_t)(3 * sp + 1) * HW_] = a2;
            cb_col[(size_t)(3 * sp + 2) * HW_] = (float)ai;
        }
    }
}

// ---- resolve: merge 4 split-candidates (1 split/thread-group), rare exact
// rescan (vectorized), write idx + quantized (gather -> LDS transpose).
// 1024 blocks x 64 points, XCD-swizzled onto the L2 holding the candidates.
__global__ __launch_bounds__(256) void vq_resolve(const float* __restrict__ x,
                                                  const float* __restrict__ cb,
                                                  const float* __restrict__ cnorm_g,
                                                  float* __restrict__ out) {
    __shared__ float tile[64 * 65];    // 16.6 KB: transpose staging
    __shared__ float pp1[4][64];       // partial m1 per split
    __shared__ float pp2[4][64];       // partial m2
    __shared__ int   ppi[4][64];       // partial idx
    __shared__ int   res_idx[64];
    __shared__ int   flist[64];
    __shared__ int   fcnt;

    const int tid  = threadIdx.x;
    const int lane = tid & 63;
    const int wid  = tid >> 6;
    const int orig = blockIdx.x;                       // 0..1023
    const int qg   = (orig & 7) * 128 + (orig >> 3);   // qg>>7 == XCD owning pg
    const int pg   = qg >> 2;
    const int col0 = ((pg & 15) << 8) + ((qg & 3) << 6);   // hw of point 0
    const int bb   = pg >> 4;
    const int t64  = tid & 63;
    const int s    = tid >> 6;         // this thread's split

    if (tid == 0) fcnt = 0;

    // parallel merge: one split per thread (3 coalesced row reads)
    const float* rdb = out + (size_t)bb * (D_ * HW_) + col0 + t64;
    const float s1 = rdb[(size_t)(3 * s + 0) * HW_];
    const float s2 = rdb[(size_t)(3 * s + 1) * HW_];
    const int   si = (int)rdb[(size_t)(3 * s + 2) * HW_];
    pp1[s][t64] = s1; pp2[s][t64] = s2; ppi[s][t64] = si;
    __syncthreads();

    // combine 4 partials (lexicographic (d2, idx) keeps np.argmin first-min)
    if (tid < 64) {
        float b1 = pp1[0][tid], b2 = pp2[0][tid];
        int   bi = ppi[0][tid];
#pragma unroll
        for (int g = 1; g < 4; ++g) {
            const float c1 = pp1[g][tid], c2 = pp2[g][tid];
            const int   ci = ppi[g][tid];
            if (c1 < b1 || (c1 == b1 && ci < bi)) { b2 = fminf(b1, c2); b1 = c1; bi = ci; }
            else                                  { b2 = fminf(b2, fminf(c1, c2)); }
        }
        res_idx[tid] = bi;
        if (b2 - b1 <= DELTA) { const int p = atomicAdd(&fcnt, 1); flist[p] = tid; }
    }
    __syncthreads();

    // exact fp32 rescan for ambiguous points (expected ~0.05/block).
    // Vectorized: float4 codebook rows, x hoisted to registers once per point.
    const int nf = fcnt;
    for (int i = wid; i < nf; i += 4) {
        const int pt = flist[i];
        const float* xr = x + (size_t)bb * (D_ * HW_) + col0 + pt;
        float xv[D_];
#pragma unroll
        for (int d = 0; d < D_; ++d) xv[d] = xr[(size_t)d * HW_];   // wave-uniform
        float b1 = INF_; int bi = 0;
        for (int c = 0; c < 16; ++c) {
            const int row = lane * 16 + c;
            const float4* cr = (const float4*)(cb + (size_t)row * D_);
            float a0 = 0.f, a1 = 0.f, a2 = 0.f, a3 = 0.f;
#pragma unroll
            for (int g = 0; g < 16; ++g) {
                const float4 cf = cr[g];
                a0 = fmaf(xv[4 * g + 0], cf.x, a0);
                a1 = fmaf(xv[4 * g + 1], cf.y, a1);
                a2 = fmaf(xv[4 * g + 2], cf.z, a2);
                a3 = fmaf(xv[4 * g + 3], cf.w, a3);
            }
            const float dot = (a0 + a1) + (a2 + a3);
            const float d2 = fmaf(-2.f, dot, cnorm_g[row]);
            if (d2 < b1) { b1 = d2; bi = row; }
        }
#pragma unroll
        for (int m = 1; m < 64; m <<= 1) {
            const float o1 = __shfl_xor(b1, m);
            const int   oi = __shfl_xor(bi, m);
            if (o1 < b1 || (o1 == b1 && oi < bi)) { b1 = o1; bi = oi; }
        }
        if (lane == 0) res_idx[pt] = bi;
    }
    __syncthreads();

    // idx output (float; exact for values <= 1023)
    if (tid < 64) out[(size_t)QOUT_ + (qg << 6) + tid] = (float)res_idx[tid];

    // Phase A: gather winning rows, lanes span d -> full 256B rows, no over-fetch
#pragma unroll
    for (int pass = 0; pass < 4; ++pass) {
        const int pt = pass * 16 + (tid >> 4);
        const int dq = tid & 15;
        const float4 v = *(const float4*)(cb + (size_t)res_idx[pt] * D_ + dq * 4);
        float* dst = &tile[pt * 65 + dq * 4];
        dst[0] = v.x; dst[1] = v.y; dst[2] = v.z; dst[3] = v.w;
    }
    __syncthreads();

    // Phase B: transpose out of LDS; per wave-instr: 64 consecutive pts at one d
    float* op = out + (size_t)bb * (D_ * HW_) + col0 + t64;
#pragma unroll
    for (int dd = 0; dd < 16; ++dd) {
        const int d = (tid >> 6) * 16 + dd;
        op[(size_t)d * HW_] = tile[t64 * 65 + d];
    }
}

extern "C" void kernel_launch(void* const* d_in, const int* in_sizes, int n_in,
                              void* d_out, int out_size, void* d_ws, size_t ws_size,
                              hipStream_t stream) {
    const float* x  = (const float*)d_in[0];   // (16, 64, 64, 64)
    const float* cb = (const float*)d_in[1];   // (1024, 64)
    float* out   = (float*)d_out;
    float* cnorm = (float*)d_ws;                       // 4 KB
    short* P     = (short*)((char*)d_ws + 4096);       // 256 KB packed bf16 codebook

    vq_pack<<<16, 256, 0, stream>>>(cb, cnorm, P);
    vq_main<<<(NPTS_ / 256) * KSPL, 512, 0, stream>>>(x, cnorm, P, out);
    vq_resolve<<<NPTS_ / 64, 256, 0, stream>>>(x, cb, cnorm, out);
}

// Round 12
// 76.226 us; speedup vs baseline: 6.3073x; 6.3073x over previous
//
#include <hip/hip_runtime.h>
#include <hip/hip_bf16.h>

#define D_ 64
#define HW_ 4096
#define K_ 1024
#define NPTS_ 65536
#define QOUT_ 4194304      // B*D*H*W, offset of idx region in d_out
#define DELTA 0.006f       // ambiguity margin; worst-case bf16-split diff ~2e-3
#define INF_ 3.4e38f

typedef short bf16x8 __attribute__((ext_vector_type(8)));
typedef float f32x4 __attribute__((ext_vector_type(4)));

__device__ __forceinline__ void gload_lds16(const float* g, float* l) {
    __builtin_amdgcn_global_load_lds((const __attribute__((address_space(1))) void*)g,
                                     (__attribute__((address_space(3))) void*)l, 16, 0, 0);
}
__device__ __forceinline__ void gload_lds4(const float* g, float* l) {
    __builtin_amdgcn_global_load_lds((const __attribute__((address_space(1))) void*)g,
                                     (__attribute__((address_space(3))) void*)l, 4, 0, 0);
}

// ---- pack kernel: cnorm + bf16 hi/lo split of (-2*cb) in MFMA-fragment order ----
// P layout (shorts): [gch(64)][ks(2)][lvl(2)][lane(64)][8]
//   code j = gch*16 + (l&15), dims d = ks*32 + (l>>4)*8 + i
__global__ __launch_bounds__(256) void vq_pack(const float* __restrict__ cb,
                                               float* __restrict__ cnorm,
                                               short* __restrict__ P) {
    const int t = blockIdx.x * 256 + threadIdx.x;   // 0..4095
    const int gch = t >> 6, l = t & 63;
    const int j  = gch * 16 + (l & 15);
    const int dg = l >> 4;
#pragma unroll
    for (int s = 0; s < 2; ++s) {
        const float* src = cb + j * D_ + s * 32 + dg * 8;
        short hb[8], lb[8];
#pragma unroll
        for (int i = 0; i < 8; ++i) {
            const float v = -2.f * src[i];
            __hip_bfloat16 h = __float2bfloat16(v);
            hb[i] = *(const short*)&h;
            const float r = v - __bfloat162float(h);
            __hip_bfloat16 lo = __float2bfloat16(r);
            lb[i] = *(const short*)&lo;
        }
        short* dh = P + ((size_t)((gch * 2 + s) * 2 + 0) * 64 + l) * 8;
        short* dl = P + ((size_t)((gch * 2 + s) * 2 + 1) * 64 + l) * 8;
#pragma unroll
        for (int i = 0; i < 8; ++i) { dh[i] = hb[i]; dl[i] = lb[i]; }
    }
    if (t < K_) {
        const float4* r = (const float4*)(cb + (size_t)t * D_);
        float s0 = 0.f, s1 = 0.f, s2 = 0.f, s3 = 0.f;
#pragma unroll
        for (int i = 0; i < 16; ++i) {
            float4 v = r[i];
            s0 = fmaf(v.x, v.x, s0); s1 = fmaf(v.y, v.y, s1);
            s2 = fmaf(v.z, v.z, s2); s3 = fmaf(v.w, v.w, s3);
        }
        cnorm[t] = (s0 + s1) + (s2 + s3);
    }
}

// ---- main: full-K streaming MFMA argmin, no split, no merge ----
// 1024 blocks x 256 thr (4 waves). Wave owns ONE 16-pt MFMA tile -> 4096
// waves = 4 waves/SIMD. Codebook streamed in 32-code chunks, double-buffered
// (2x8KB LDS). (m1,m2,i1) stay in registers across all 1024 codes; final idx
// written directly with ambiguity flag encoded in the sign.
__global__ __launch_bounds__(256, 4) void vq_main(const float* __restrict__ x,
                                                  const float* __restrict__ cnorm_g,
                                                  const short* __restrict__ P,
                                                  float* __restrict__ out) {
    __shared__ short cbuf[2][4096];   // 2 x 8 KB: 32 codes per buffer
    __shared__ float cnt[K_];         // 4 KB

    const int tid  = threadIdx.x;
    const int lane = tid & 63;
    const int wid  = tid >> 6;        // 0..3
    const int pg   = blockIdx.x;      // 0..1023
    const int bb   = pg >> 6;
    const int hw0  = (pg & 63) << 6;

    const float* Pf = (const float*)P;

    // stage cnorm (4 KB) + chunk 0 (8 KB)
#pragma unroll
    for (int i = 0; i < 4; ++i)
        gload_lds4(cnorm_g + i * 256 + wid * 64 + lane, cnt + i * 256 + wid * 64);
#pragma unroll
    for (int r = 0; r < 2; ++r)
        gload_lds16(Pf + r * 1024 + wid * 256 + lane * 4,
                    (float*)cbuf[0] + r * 1024 + wid * 256);

    // load + split x fragment: wave owns 16 points, lane holds point (l&15),
    // dims (l>>4)*8..+7 per k-step s
    bf16x8 ah[2], al[2];
    {
        const float* xb = x + (size_t)bb * (D_ * HW_) + hw0;
        const int p_l = wid * 16 + (lane & 15);
#pragma unroll
        for (int s = 0; s < 2; ++s) {
            const int d0 = s * 32 + (lane >> 4) * 8;
#pragma unroll
            for (int i = 0; i < 8; ++i) {
                const float v = xb[(size_t)(d0 + i) * HW_ + p_l];
                __hip_bfloat16 h = __float2bfloat16(v);
                ah[s][i] = *(const short*)&h;
                const float r = v - __bfloat162float(h);
                __hip_bfloat16 lo = __float2bfloat16(r);
                al[s][i] = *(const short*)&lo;
            }
        }
    }
    asm volatile("s_waitcnt vmcnt(0)" ::: "memory");
    __syncthreads();

    float m1[4], m2[4];
    int   i1[4];
#pragma unroll
    for (int q = 0; q < 4; ++q) { m1[q] = INF_; m2[q] = INF_; i1[q] = 0; }

    int cur = 0;
#pragma unroll 1
    for (int c = 0; c < 32; ++c) {
        // prefetch next chunk first: lands under this chunk's compute
        if (c + 1 < 32) {
            const float* src = Pf + (size_t)(c + 1) * 2048;
            float* dst = (float*)cbuf[cur ^ 1];
#pragma unroll
            for (int r = 0; r < 2; ++r)
                gload_lds16(src + r * 1024 + wid * 256 + lane * 4,
                            dst + r * 1024 + wid * 256);
        }
        const bf16x8* fr = (const bf16x8*)cbuf[cur];
#pragma unroll
        for (int u = 0; u < 2; ++u) {
            const int kc = c * 32 + u * 16 + (lane & 15);
            const float cn = cnt[kc];
            bf16x8 bh0 = fr[(u * 4 + 0) * 64 + lane];
            bf16x8 bl0 = fr[(u * 4 + 1) * 64 + lane];
            bf16x8 bh1 = fr[(u * 4 + 2) * 64 + lane];
            bf16x8 bl1 = fr[(u * 4 + 3) * 64 + lane];
            f32x4 aa = {0.f, 0.f, 0.f, 0.f};   // s=0 terms (3-deep chain)
            f32x4 ab = {0.f, 0.f, 0.f, 0.f};   // s=1 terms (3-deep chain)
            aa = __builtin_amdgcn_mfma_f32_16x16x32_bf16(ah[0], bh0, aa, 0, 0, 0);
            ab = __builtin_amdgcn_mfma_f32_16x16x32_bf16(ah[1], bh1, ab, 0, 0, 0);
            aa = __builtin_amdgcn_mfma_f32_16x16x32_bf16(al[0], bh0, aa, 0, 0, 0);
            ab = __builtin_amdgcn_mfma_f32_16x16x32_bf16(al[1], bh1, ab, 0, 0, 0);
            aa = __builtin_amdgcn_mfma_f32_16x16x32_bf16(ah[0], bl0, aa, 0, 0, 0);
            ab = __builtin_amdgcn_mfma_f32_16x16x32_bf16(ah[1], bl1, ab, 0, 0, 0);
#pragma unroll
            for (int r = 0; r < 4; ++r) {
                const float d2 = cn + (aa[r] + ab[r]);
                const bool lt = d2 < m1[r];
                m2[r] = fminf(m2[r], fmaxf(m1[r], d2));  // min(m2, loser of (m1,d2))
                m1[r] = fminf(m1[r], d2);
                i1[r] = lt ? kc : i1[r];
            }
        }
        __syncthreads();   // prefetch complete + all waves done reading cur
        cur ^= 1;
    }

    // cross-lane (m1,i1,m2) reduce over the 16 lanes sharing (lane>>4),
    // then write FINAL idx with ambiguity flag in the sign.
#pragma unroll
    for (int q = 0; q < 4; ++q) {
        float a1 = m1[q], a2 = m2[q];
        int   ai = i1[q];
#pragma unroll
        for (int m = 1; m < 16; m <<= 1) {
            const float o1 = __shfl_xor(a1, m);
            const int   oi = __shfl_xor(ai, m);
            const float o2 = __shfl_xor(a2, m);
            const float nm2 = fminf(fminf(a2, o2), fmaxf(a1, o1));
            if (o1 < a1 || (o1 == a1 && oi < ai)) { a1 = o1; ai = oi; }
            a2 = nm2;
        }
        if ((lane & 15) == 0) {
            const int pt = wid * 16 + 4 * (lane >> 4) + q;
            const bool amb = (a2 - a1 <= DELTA);
            out[(size_t)QOUT_ + pg * 64 + pt] = amb ? -(float)(ai + 1) : (float)ai;
        }
    }
}

// ---- resolve: decode flagged idx, rare exact rescan, rewrite clean idx,
// gather + LDS transpose + coalesced quantized write. 1024 blocks x 64 pts.
__global__ __launch_bounds__(256) void vq_resolve(const float* __restrict__ x,
                                                  const float* __restrict__ cb,
                                                  const float* __restrict__ cnorm_g,
                                                  float* __restrict__ out) {
    __shared__ float tile[64 * 65];    // 16.6 KB: transpose staging
    __shared__ int res_idx[64];
    __shared__ int flist[64];
    __shared__ int fcnt;

    const int tid  = threadIdx.x;
    const int lane = tid & 63;
    const int wid  = tid >> 6;
    const int qg   = blockIdx.x;       // 0..1023
    const int bb   = qg >> 6;
    const int col0 = (qg & 63) << 6;   // hw of point 0
    const int t64  = tid & 63;

    if (tid == 0) fcnt = 0;
    __syncthreads();

    // decode idx + flag (sign-encoded by vq_main)
    if (tid < 64) {
        const float v = out[(size_t)QOUT_ + qg * 64 + tid];
        const bool fl = v < 0.f;
        res_idx[tid] = fl ? (int)(-v) - 1 : (int)v;
        if (fl) { const int p = atomicAdd(&fcnt, 1); flist[p] = tid; }
    }
    __syncthreads();

    // exact fp32 rescan for ambiguous points (expected ~0.05/block).
    // Vectorized: float4 codebook rows, x hoisted to registers once per point.
    const int nf = fcnt;
    for (int i = wid; i < nf; i += 4) {
        const int pt = flist[i];
        const float* xr = x + (size_t)bb * (D_ * HW_) + col0 + pt;
        float xv[D_];
#pragma unroll
        for (int d = 0; d < D_; ++d) xv[d] = xr[(size_t)d * HW_];   // wave-uniform
        float b1 = INF_; int bi = 0;
        for (int c = 0; c < 16; ++c) {
            const int row = lane * 16 + c;
            const float4* cr = (const float4*)(cb + (size_t)row * D_);
            float a0 = 0.f, a1 = 0.f, a2 = 0.f, a3 = 0.f;
#pragma unroll
            for (int g = 0; g < 16; ++g) {
                const float4 cf = cr[g];
                a0 = fmaf(xv[4 * g + 0], cf.x, a0);
                a1 = fmaf(xv[4 * g + 1], cf.y, a1);
                a2 = fmaf(xv[4 * g + 2], cf.z, a2);
                a3 = fmaf(xv[4 * g + 3], cf.w, a3);
            }
            const float dot = (a0 + a1) + (a2 + a3);
            const float d2 = fmaf(-2.f, dot, cnorm_g[row]);
            if (d2 < b1) { b1 = d2; bi = row; }
        }
#pragma unroll
        for (int m = 1; m < 64; m <<= 1) {
            const float o1 = __shfl_xor(b1, m);
            const int   oi = __shfl_xor(bi, m);
            if (o1 < b1 || (o1 == b1 && oi < bi)) { b1 = o1; bi = oi; }
        }
        if (lane == 0) res_idx[pt] = bi;
    }
    __syncthreads();

    // clean idx output (float; exact for values <= 1023)
    if (tid < 64) out[(size_t)QOUT_ + qg * 64 + tid] = (float)res_idx[tid];

    // Phase A: gather winning rows, lanes span d -> full 256B rows, no over-fetch
#pragma unroll
    for (int pass = 0; pass < 4; ++pass) {
        const int pt = pass * 16 + (tid >> 4);
        const int dq = tid & 15;
        const float4 v = *(const float4*)(cb + (size_t)res_idx[pt] * D_ + dq * 4);
        float* dst = &tile[pt * 65 + dq * 4];
        dst[0] = v.x; dst[1] = v.y; dst[2] = v.z; dst[3] = v.w;
    }
    __syncthreads();

    // Phase B: transpose out of LDS; per wave-instr: 64 consecutive pts at one d
    float* op = out + (size_t)bb * (D_ * HW_) + col0 + t64;
#pragma unroll
    for (int dd = 0; dd < 16; ++dd) {
        const int d = (tid >> 6) * 16 + dd;
        op[(size_t)d * HW_] = tile[t64 * 65 + d];
    }
}

extern "C" void kernel_launch(void* const* d_in, const int* in_sizes, int n_in,
                              void* d_out, int out_size, void* d_ws, size_t ws_size,
                              hipStream_t stream) {
    const float* x  = (const float*)d_in[0];   // (16, 64, 64, 64)
    const float* cb = (const float*)d_in[1];   // (1024, 64)
    float* out   = (float*)d_out;
    float* cnorm = (float*)d_ws;                       // 4 KB
    short* P     = (short*)((char*)d_ws + 4096);       // 256 KB packed bf16 codebook

    vq_pack<<<16, 256, 0, stream>>>(cb, cnorm, P);
    vq_main<<<NPTS_ / 64, 256, 0, stream>>>(x, cnorm, P, out);
    vq_resolve<<<NPTS_ / 64, 256, 0, stream>>>(x, cb, cnorm, out);
}